// Round 5
// baseline (862.259 us; speedup 1.0000x reference)
//
#include <hip/hip_runtime.h>
#include <hip/hip_bf16.h>

typedef __attribute__((ext_vector_type(4))) float floatx4;
typedef __attribute__((ext_vector_type(8))) __bf16 bf16x8;
typedef unsigned short ushort_t;

#define NENT  700
#define EMB   256
#define KDIM  1024
#define NDIM  512
#define HROWS 712   // 89*8: every row written by hab_kernel
#define SHS   1028  // LDS f32 row stride: 1024+4 -> conflict-free-equivalent groups

// ws byte offsets — total ~4.69 MB
#define WS_HA   0
#define WS_HB   (WS_HA + HROWS*KDIM*2)
#define WS_W2C  (WS_HB + HROWS*KDIM*2)
#define WS_ENT  (WS_W2C + NDIM*KDIM*2)
#define WS_FLAG (WS_ENT + NENT*EMB*4)

__device__ __forceinline__ float ldin(const void* p, int i, int isbf) {
    return isbf ? __bfloat162float(((const __hip_bfloat16*)p)[i])
                : ((const float*)p)[i];
}

// ---------------- stage 0: detect input dtype (f32 vs bf16) ----------------
__global__ void detect_kernel(const ushort_t* __restrict__ w, int* __restrict__ flag) {
    if (threadIdx.x == 0) {
        int cnt = 0;
        for (int i = 0; i < 128; ++i) {
            int e = (w[2*i] >> 7) & 0xFF;
            if (e >= 100 && e <= 126) cnt++;
        }
        *flag = (cnt >= 96) ? 1 : 0;   // 1 = bf16 inputs, 0 = f32
    }
}

// ---------------- stage 1: ent = E @ W_ent, 8 rows/block ----------------
__global__ void ent_kernel(const void* __restrict__ E, const void* __restrict__ Went,
                           const int* __restrict__ flag,
                           float* __restrict__ ent, void* __restrict__ out) {
    int ib = blockIdx.x * 8, t = threadIdx.x;
    int isbf = *flag;
    __shared__ float rows[8][EMB];
#pragma unroll
    for (int r = 0; r < 8; ++r) {
        int i = ib + r;
        rows[r][t] = (i < NENT) ? ldin(E, i*EMB + t, isbf) : 0.f;
    }
    __syncthreads();
    float acc[8] = {0.f,0.f,0.f,0.f,0.f,0.f,0.f,0.f};
    if (isbf) {
        const __hip_bfloat16* W = (const __hip_bfloat16*)Went;
        for (int k = 0; k < EMB; ++k) {
            float w = __bfloat162float(W[k*EMB + t]);
#pragma unroll
            for (int r = 0; r < 8; ++r) acc[r] += rows[r][k] * w;
        }
    } else {
        const float* W = (const float*)Went;
        for (int k = 0; k < EMB; ++k) {
            float w = W[k*EMB + t];
#pragma unroll
            for (int r = 0; r < 8; ++r) acc[r] += rows[r][k] * w;
        }
    }
#pragma unroll
    for (int r = 0; r < 8; ++r) {
        int i = ib + r;
        if (i < NENT) {
            ent[i*EMB + t] = acc[r];
            if (i < 200) {
                if (isbf) ((__hip_bfloat16*)out)[680000 + i*EMB + t] = __float2bfloat16(acc[r]);
                else      ((float*)out)[680000 + i*EMB + t] = acc[r];
            }
        }
    }
}

// ---------------- stage 2: HA = ent@W1[:256] + b1 ; HB = ent@W1[256:] (bf16 out) ----------------
__global__ void hab_kernel(const float* __restrict__ ent,
                           const void* __restrict__ W1, const void* __restrict__ b1,
                           const int* __restrict__ flag,
                           __hip_bfloat16* __restrict__ HA, __hip_bfloat16* __restrict__ HB) {
    int part = blockIdx.y;
    int ib = blockIdx.x * 8;
    int t = threadIdx.x;
    int isbf = *flag;
    __shared__ float rows[8][EMB];
#pragma unroll
    for (int r = 0; r < 8; ++r) {
        int i = ib + r;
        rows[r][t] = (i < NENT) ? ent[i*EMB + t] : 0.f;
    }
    __syncthreads();
    float acc[8][4];
#pragma unroll
    for (int r = 0; r < 8; ++r)
#pragma unroll
        for (int p = 0; p < 4; ++p) acc[r][p] = 0.f;

    int wbase = part*EMB*KDIM;
    if (isbf) {
        const __hip_bfloat16* W = (const __hip_bfloat16*)W1;
        for (int k = 0; k < EMB; ++k) {
            float w[4];
#pragma unroll
            for (int p = 0; p < 4; ++p) w[p] = __bfloat162float(W[wbase + k*KDIM + t + p*256]);
#pragma unroll
            for (int r = 0; r < 8; ++r) {
                float e = rows[r][k];
#pragma unroll
                for (int p = 0; p < 4; ++p) acc[r][p] += e * w[p];
            }
        }
    } else {
        const float* W = (const float*)W1;
        for (int k = 0; k < EMB; ++k) {
            float w[4];
#pragma unroll
            for (int p = 0; p < 4; ++p) w[p] = W[wbase + k*KDIM + t + p*256];
#pragma unroll
            for (int r = 0; r < 8; ++r) {
                float e = rows[r][k];
#pragma unroll
                for (int p = 0; p < 4; ++p) acc[r][p] += e * w[p];
            }
        }
    }
    __hip_bfloat16* HX = part ? HB : HA;
#pragma unroll
    for (int r = 0; r < 8; ++r) {
#pragma unroll
        for (int p = 0; p < 4; ++p) {
            int n = t + p*256;
            float v = acc[r][p];
            if (!part) v += ldin(b1, n, isbf);
            HX[(ib + r)*KDIM + n] = __float2bfloat16(v);
        }
    }
}

// ---------------- prep: W2C[kc][n][ko] = bf16(W2[kc*32+ko][n]) (k-chunk-contiguous) ----------------
__global__ void prep_kernel(const void* __restrict__ W2, const int* __restrict__ flag,
                            __hip_bfloat16* __restrict__ W2C) {
    int g = blockIdx.x*256 + threadIdx.x;    // 524288 total; n fast -> coalesced reads
    int n = g & 511, k = g >> 9;
    int o = (k >> 5)*16384 + n*32 + (k & 31);
    W2C[o] = __float2bfloat16(ldin(W2, k*NDIM + n, *flag));
}

union U8 { bf16x8 v; unsigned u[4]; };

// A-frag from 8 f32 ha + 8 f32 hb: relu(ha+hb) -> bf16 round-half-up pair-packed
__device__ __forceinline__ bf16x8 mk_af(float4 a0, float4 a1, float4 b0, float4 b1) {
    U8 r;
    float x0, x1; unsigned u0, u1;
    x0 = fmaxf(a0.x + b0.x, 0.f); x1 = fmaxf(a0.y + b0.y, 0.f);
    u0 = __float_as_uint(x0) + 0x8000u; u1 = __float_as_uint(x1) + 0x8000u;
    r.u[0] = (u0 >> 16) | (u1 & 0xFFFF0000u);
    x0 = fmaxf(a0.z + b0.z, 0.f); x1 = fmaxf(a0.w + b0.w, 0.f);
    u0 = __float_as_uint(x0) + 0x8000u; u1 = __float_as_uint(x1) + 0x8000u;
    r.u[1] = (u0 >> 16) | (u1 & 0xFFFF0000u);
    x0 = fmaxf(a1.x + b1.x, 0.f); x1 = fmaxf(a1.y + b1.y, 0.f);
    u0 = __float_as_uint(x0) + 0x8000u; u1 = __float_as_uint(x1) + 0x8000u;
    r.u[2] = (u0 >> 16) | (u1 & 0xFFFF0000u);
    x0 = fmaxf(a1.z + b1.z, 0.f); x1 = fmaxf(a1.w + b1.w, 0.f);
    u0 = __float_as_uint(x0) + 0x8000u; u1 = __float_as_uint(x1) + 0x8000u;
    r.u[3] = (u0 >> 16) | (u1 & 0xFFFF0000u);
    return r.v;
}

#define MFMA(a, b, c) __builtin_amdgcn_mfma_f32_16x16x32_bf16((a), (b), (c), 0, 0, 0)

// ---------------- main: fused pair MLP, 512 thr, tile m128(8i x 16j) x n512 ----------------
__global__ __launch_bounds__(512, 2) void pair_kernel(
        const ushort_t* __restrict__ HA, const ushort_t* __restrict__ HB,
        const ushort_t* __restrict__ W2C,
        const void* __restrict__ b2, const void* __restrict__ W3, const void* __restrict__ b3,
        const int* __restrict__ flag, void* __restrict__ out) {

    const int blkEnd[10] = {325,650,900,1150,1400,1725,2050,2297,2544,2791};
    const int aB[10]  = {0,0,0,0,200,200,200,550,400,400};
    const int bB[10]  = {200,0,400,550,400,200,0,0,200,0};
    const int NaT[10] = {200,200,200,200,200,200,200,150,150,150};
    const int NbT[10] = {200,200,150,150,150,200,200,200,200,200};
    const int jTl[10] = {13,13,10,10,10,13,13,13,13,13};
    const int oOf[10] = {0,80000,160000,220000,280000,340000,420000,500000,560000,620000};

    __shared__ float sHA[8*SHS];     // 32,896 B
    __shared__ float sHB[16*SHS];    // 65,792 B
    __shared__ float lgt[2][128][2]; //  2,048 B

    int bid = blockIdx.x;
    int ty = 0;
    while (bid >= blkEnd[ty]) ty++;
    int lb = bid - (ty ? blkEnd[ty-1] : 0);
    int jT = jTl[ty];
    int it = lb / jT;
    int jt = lb - it*jT;
    int i0 = aB[ty] + it*8;    // 8 'a' rows per block
    int j0 = bB[ty] + jt*16;   // 16 'b' rows per block

    int tid  = threadIdx.x;
    int lane = tid & 63;
    int w    = tid >> 6;       // 0..7
    int wm   = w & 3;          // m-wave: i-rows {i0+2wm, i0+2wm+1}
    int wn2  = w >> 2;         // n-wave: n-half
    int l15  = lane & 15;
    int quad = lane >> 4;
    int isbf = *flag;

    // ---- stage HB (16 rows) and HA (8 rows) into LDS as f32 ----
#pragma unroll
    for (int ii = 0; ii < 4; ++ii) {           // 2048 bf16x8 frags
        int fr = tid + ii*512;
        int r = fr >> 7, c = (fr & 127) << 3;
        bf16x8 v = *(const bf16x8*)(HB + (j0 + r)*KDIM + c);
        float* d = sHB + r*SHS + c;
#pragma unroll
        for (int j = 0; j < 8; ++j) d[j] = (float)v[j];
    }
#pragma unroll
    for (int ii = 0; ii < 2; ++ii) {           // 1024 frags
        int fr = tid + ii*512;
        int r = fr >> 7, c = (fr & 127) << 3;
        bf16x8 v = *(const bf16x8*)(HA + (i0 + r)*KDIM + c);
        float* d = sHA + r*SHS + c;
#pragma unroll
        for (int j = 0; j < 8; ++j) d[j] = (float)v[j];
    }
    __syncthreads();

    // B pointer: frag (kc,nf) at Bp + kc*16384 + nf*512 (elements)
    const ushort_t* Bp = W2C + (wn2*256 + l15)*32 + quad*8;
    const float* hbp  = sHB + l15*SHS + quad*8;
    const float* hap0 = sHA + (wm*2    )*SHS + quad*8;
    const float* hap1 = sHA + (wm*2 + 1)*SHS + quad*8;

    floatx4 acc[2][16];
#pragma unroll
    for (int f = 0; f < 2; ++f)
#pragma unroll
        for (int nf = 0; nf < 16; ++nf) acc[f][nf] = (floatx4){0.f,0.f,0.f,0.f};

    bf16x8 X0, X1, X2, X3, Y0, Y1, Y2, Y3;
    X0 = *(const bf16x8*)(Bp + 0*512);
    X1 = *(const bf16x8*)(Bp + 1*512);
    X2 = *(const bf16x8*)(Bp + 2*512);
    X3 = *(const bf16x8*)(Bp + 3*512);

#pragma unroll 2
    for (int kc = 0; kc < 32; ++kc) {
        const ushort_t* Bk = Bp + kc*16384;
        int kk = kc*32;
        // phase0 prefetch (nf 4..7)
        Y0 = *(const bf16x8*)(Bk + 4*512);
        Y1 = *(const bf16x8*)(Bk + 5*512);
        Y2 = *(const bf16x8*)(Bk + 6*512);
        Y3 = *(const bf16x8*)(Bk + 7*512);
        // A-gen (f32 LDS, no cvt)
        float4 hb0 = *(const float4*)(hbp + kk);
        float4 hb1 = *(const float4*)(hbp + kk + 4);
        float4 a00 = *(const float4*)(hap0 + kk);
        float4 a01 = *(const float4*)(hap0 + kk + 4);
        float4 a10 = *(const float4*)(hap1 + kk);
        float4 a11 = *(const float4*)(hap1 + kk + 4);
        bf16x8 af0 = mk_af(a00, a01, hb0, hb1);
        bf16x8 af1 = mk_af(a10, a11, hb0, hb1);
        // phase0 MFMA (nf 0..3 from X)
        acc[0][0] = MFMA(af0, X0, acc[0][0]);  acc[1][0] = MFMA(af1, X0, acc[1][0]);
        acc[0][1] = MFMA(af0, X1, acc[0][1]);  acc[1][1] = MFMA(af1, X1, acc[1][1]);
        acc[0][2] = MFMA(af0, X2, acc[0][2]);  acc[1][2] = MFMA(af1, X2, acc[1][2]);
        acc[0][3] = MFMA(af0, X3, acc[0][3]);  acc[1][3] = MFMA(af1, X3, acc[1][3]);
        // phase1: prefetch nf 8..11 into X, consume Y (nf 4..7)
        X0 = *(const bf16x8*)(Bk + 8*512);
        X1 = *(const bf16x8*)(Bk + 9*512);
        X2 = *(const bf16x8*)(Bk + 10*512);
        X3 = *(const bf16x8*)(Bk + 11*512);
        acc[0][4] = MFMA(af0, Y0, acc[0][4]);  acc[1][4] = MFMA(af1, Y0, acc[1][4]);
        acc[0][5] = MFMA(af0, Y1, acc[0][5]);  acc[1][5] = MFMA(af1, Y1, acc[1][5]);
        acc[0][6] = MFMA(af0, Y2, acc[0][6]);  acc[1][6] = MFMA(af1, Y2, acc[1][6]);
        acc[0][7] = MFMA(af0, Y3, acc[0][7]);  acc[1][7] = MFMA(af1, Y3, acc[1][7]);
        // phase2: prefetch nf 12..15 into Y, consume X (nf 8..11)
        Y0 = *(const bf16x8*)(Bk + 12*512);
        Y1 = *(const bf16x8*)(Bk + 13*512);
        Y2 = *(const bf16x8*)(Bk + 14*512);
        Y3 = *(const bf16x8*)(Bk + 15*512);
        acc[0][8]  = MFMA(af0, X0, acc[0][8]);   acc[1][8]  = MFMA(af1, X0, acc[1][8]);
        acc[0][9]  = MFMA(af0, X1, acc[0][9]);   acc[1][9]  = MFMA(af1, X1, acc[1][9]);
        acc[0][10] = MFMA(af0, X2, acc[0][10]);  acc[1][10] = MFMA(af1, X2, acc[1][10]);
        acc[0][11] = MFMA(af0, X3, acc[0][11]);  acc[1][11] = MFMA(af1, X3, acc[1][11]);
        // phase3: prefetch next kc's nf 0..3 into X, consume Y (nf 12..15)
        const ushort_t* Bn = Bp + (((kc + 1) & 31))*16384;
        X0 = *(const bf16x8*)(Bn + 0*512);
        X1 = *(const bf16x8*)(Bn + 1*512);
        X2 = *(const bf16x8*)(Bn + 2*512);
        X3 = *(const bf16x8*)(Bn + 3*512);
        acc[0][12] = MFMA(af0, Y0, acc[0][12]);  acc[1][12] = MFMA(af1, Y0, acc[1][12]);
        acc[0][13] = MFMA(af0, Y1, acc[0][13]);  acc[1][13] = MFMA(af1, Y1, acc[1][13]);
        acc[0][14] = MFMA(af0, Y2, acc[0][14]);  acc[1][14] = MFMA(af1, Y2, acc[1][14]);
        acc[0][15] = MFMA(af0, Y3, acc[0][15]);  acc[1][15] = MFMA(af1, Y3, acc[1][15]);
    }

    // epilogue: h2 = relu(acc + b2); logits += h2 * W3; reduce over n (in-wave 16 lanes)
#pragma unroll
    for (int f = 0; f < 2; ++f) {
        float s0[4] = {0.f,0.f,0.f,0.f};
        float s1[4] = {0.f,0.f,0.f,0.f};
#pragma unroll
        for (int nf = 0; nf < 16; ++nf) {
            int n = wn2*256 + nf*16 + l15;
            float b2v = ldin(b2, n, isbf);
            float wa  = ldin(W3, 2*n, isbf);
            float wb  = ldin(W3, 2*n+1, isbf);
            floatx4 c = acc[f][nf];
#pragma unroll
            for (int r = 0; r < 4; ++r) {
                float v = fmaxf(c[r] + b2v, 0.f);
                s0[r] += v * wa;
                s1[r] += v * wb;
            }
        }
#pragma unroll
        for (int off = 1; off < 16; off <<= 1) {
#pragma unroll
            for (int r = 0; r < 4; ++r) {
                s0[r] += __shfl_xor(s0[r], off, 64);
                s1[r] += __shfl_xor(s1[r], off, 64);
            }
        }
        if (l15 == 0) {
#pragma unroll
            for (int r = 0; r < 4; ++r) {
                int p = (wm*2 + f)*16 + quad*4 + r;   // pair local: i_local*16 + j
                lgt[wn2][p][0] = s0[r];
                lgt[wn2][p][1] = s1[r];
            }
        }
    }
    __syncthreads();

    if (tid < 128) {
        int p = tid;
        float l0 = lgt[0][p][0] + lgt[1][p][0] + ldin(b3, 0, isbf);
        float l1 = lgt[0][p][1] + lgt[1][p][1] + ldin(b3, 1, isbf);
        float mx = fmaxf(l0, l1);
        float e0 = __expf(l0 - mx), e1 = __expf(l1 - mx);
        float inv = 1.f / (e0 + e1);
        int pi = it*8 + (p >> 4), pj = jt*16 + (p & 15);
        if (pi < NaT[ty] && pj < NbT[ty]) {
            int o = oOf[ty] + (pi*NbT[ty] + pj)*2;
            if (isbf) {
                __hip_bfloat16* ob = (__hip_bfloat16*)out;
                ob[o]   = __float2bfloat16(e0 * inv);
                ob[o+1] = __float2bfloat16(e1 * inv);
            } else {
                float* of = (float*)out;
                of[o]   = e0 * inv;
                of[o+1] = e1 * inv;
            }
        }
    }
}

extern "C" void kernel_launch(void* const* d_in, const int* in_sizes, int n_in,
                              void* d_out, int out_size, void* d_ws, size_t ws_size,
                              hipStream_t stream) {
    const void* E    = d_in[1];
    const void* Went = d_in[3];
    const void* W1   = d_in[5];
    const void* b1   = d_in[6];
    const void* W2   = d_in[7];
    const void* b2   = d_in[8];
    const void* W3   = d_in[9];
    const void* b3   = d_in[10];

    char* ws = (char*)d_ws;
    __hip_bfloat16* HA   = (__hip_bfloat16*)(ws + WS_HA);
    __hip_bfloat16* HB   = (__hip_bfloat16*)(ws + WS_HB);
    __hip_bfloat16* W2C  = (__hip_bfloat16*)(ws + WS_W2C);
    float*          entf = (float*)(ws + WS_ENT);
    int*            flag = (int*)(ws + WS_FLAG);

    detect_kernel<<<dim3(1), dim3(64), 0, stream>>>((const ushort_t*)E, flag);
    ent_kernel<<<dim3(88), dim3(256), 0, stream>>>(E, Went, flag, entf, d_out);
    hab_kernel<<<dim3(89, 2), dim3(256), 0, stream>>>(entf, W1, b1, flag, HA, HB);
    prep_kernel<<<dim3(2048), dim3(256), 0, stream>>>(W2, flag, W2C);
    pair_kernel<<<dim3(2791), dim3(512), 0, stream>>>((const ushort_t*)HA, (const ushort_t*)HB,
                                                      (const ushort_t*)W2C, b2, W3, b3, flag, d_out);
}

// Round 6
// 675.180 us; speedup vs baseline: 1.2771x; 1.2771x over previous
//
#include <hip/hip_runtime.h>
#include <hip/hip_bf16.h>

typedef __attribute__((ext_vector_type(4))) float floatx4;
typedef __attribute__((ext_vector_type(8))) __bf16 bf16x8;
typedef __attribute__((ext_vector_type(4))) __bf16 bf16x4;
typedef unsigned short ushort_t;

#define NENT  700
#define EMB   256
#define KDIM  1024
#define NDIM  512
#define HROWS 712   // 89*8: every row written by hab_kernel
#define SBS   1028  // sHB f32 row stride (words): +4 -> 2-way (free) b128 reads

// ws byte offsets — total ~4.68 MB
#define WS_HA   0
#define WS_HB   (WS_HA + HROWS*KDIM*2)
#define WS_W2S  (WS_HB + HROWS*KDIM*2)
#define WS_ENT  (WS_W2S + NDIM*KDIM*2)
#define WS_FLAG (WS_ENT + NENT*EMB*4)

__device__ __forceinline__ float ldin(const void* p, int i, int isbf) {
    return isbf ? __bfloat162float(((const __hip_bfloat16*)p)[i])
                : ((const float*)p)[i];
}

// ---------------- stage 0: detect input dtype (f32 vs bf16), 1 wave ----------------
__global__ void detect_kernel(const ushort_t* __restrict__ w, int* __restrict__ flag) {
    int t = threadIdx.x;                    // 64 threads
    int e = (w[2*t] >> 7) & 0xFF;           // exponent field of even 16-bit word
    unsigned long long m = __ballot(e >= 100 && e <= 126);
    if (t == 0) *flag = (__popcll(m) >= 48) ? 1 : 0;   // bf16 ~64 hits, f32 ~7
}

// ---------------- stage 1: ent = E @ W_ent, 8 rows/block ----------------
__global__ void ent_kernel(const void* __restrict__ E, const void* __restrict__ Went,
                           const int* __restrict__ flag,
                           float* __restrict__ ent, void* __restrict__ out) {
    int ib = blockIdx.x * 8, t = threadIdx.x;
    int isbf = *flag;
    __shared__ float rows[8][EMB];
#pragma unroll
    for (int r = 0; r < 8; ++r) {
        int i = ib + r;
        rows[r][t] = (i < NENT) ? ldin(E, i*EMB + t, isbf) : 0.f;
    }
    __syncthreads();
    float acc[8] = {0.f,0.f,0.f,0.f,0.f,0.f,0.f,0.f};
    if (isbf) {
        const __hip_bfloat16* W = (const __hip_bfloat16*)Went;
        for (int k = 0; k < EMB; ++k) {
            float w = __bfloat162float(W[k*EMB + t]);
#pragma unroll
            for (int r = 0; r < 8; ++r) acc[r] += rows[r][k] * w;
        }
    } else {
        const float* W = (const float*)Went;
        for (int k = 0; k < EMB; ++k) {
            float w = W[k*EMB + t];
#pragma unroll
            for (int r = 0; r < 8; ++r) acc[r] += rows[r][k] * w;
        }
    }
#pragma unroll
    for (int r = 0; r < 8; ++r) {
        int i = ib + r;
        if (i < NENT) {
            ent[i*EMB + t] = acc[r];
            if (i < 200) {
                if (isbf) ((__hip_bfloat16*)out)[680000 + i*EMB + t] = __float2bfloat16(acc[r]);
                else      ((float*)out)[680000 + i*EMB + t] = acc[r];
            }
        }
    }
}

// ---------------- stage 2: HA = ent@W1[:256] + b1 ; HB = ent@W1[256:] (bf16 out) ----------------
__global__ void hab_kernel(const float* __restrict__ ent,
                           const void* __restrict__ W1, const void* __restrict__ b1,
                           const int* __restrict__ flag,
                           __hip_bfloat16* __restrict__ HA, __hip_bfloat16* __restrict__ HB) {
    int part = blockIdx.y;
    int ib = blockIdx.x * 8;
    int t = threadIdx.x;
    int isbf = *flag;
    __shared__ float rows[8][EMB];
#pragma unroll
    for (int r = 0; r < 8; ++r) {
        int i = ib + r;
        rows[r][t] = (i < NENT) ? ent[i*EMB + t] : 0.f;
    }
    __syncthreads();
    float acc[8][4];
#pragma unroll
    for (int r = 0; r < 8; ++r)
#pragma unroll
        for (int p = 0; p < 4; ++p) acc[r][p] = 0.f;

    int wbase = part*EMB*KDIM;
    if (isbf) {
        const __hip_bfloat16* W = (const __hip_bfloat16*)W1;
        for (int k = 0; k < EMB; ++k) {
            float w[4];
#pragma unroll
            for (int p = 0; p < 4; ++p) w[p] = __bfloat162float(W[wbase + k*KDIM + t + p*256]);
#pragma unroll
            for (int r = 0; r < 8; ++r) {
                float e = rows[r][k];
#pragma unroll
                for (int p = 0; p < 4; ++p) acc[r][p] += e * w[p];
            }
        }
    } else {
        const float* W = (const float*)W1;
        for (int k = 0; k < EMB; ++k) {
            float w[4];
#pragma unroll
            for (int p = 0; p < 4; ++p) w[p] = W[wbase + k*KDIM + t + p*256];
#pragma unroll
            for (int r = 0; r < 8; ++r) {
                float e = rows[r][k];
#pragma unroll
                for (int p = 0; p < 4; ++p) acc[r][p] += e * w[p];
            }
        }
    }
    __hip_bfloat16* HX = part ? HB : HA;
#pragma unroll
    for (int r = 0; r < 8; ++r) {
#pragma unroll
        for (int p = 0; p < 4; ++p) {
            int n = t + p*256;
            float v = acc[r][p];
            if (!part) v += ldin(b1, n, isbf);
            HX[(ib + r)*KDIM + n] = __float2bfloat16(v);
        }
    }
}

// ---------------- prep: W2S = W2 in per-fragment lane order ----------------
// chunk kc (32k), frag f (16n x 32k, 1KB): W2S[((kc*32+f)*64 + lane)*8 + j]
//   = bf16(W2[(kc*32 + (lane>>4)*8 + j)*512 + f*16 + (lane&15)])
__global__ void prep_kernel(const void* __restrict__ W2, const int* __restrict__ flag,
                            __hip_bfloat16* __restrict__ W2S) {
    int g = blockIdx.x*256 + threadIdx.x;     // 65536 threads
    int lane = g & 63, f = (g >> 6) & 31, kc = g >> 11;
    int l15 = lane & 15, quad = lane >> 4;
    int n = f*16 + l15;
    int isbf = *flag;
    bf16x8 v;
#pragma unroll
    for (int j = 0; j < 8; ++j) {
        int k = kc*32 + quad*8 + j;
        v[j] = (__bf16)ldin(W2, k*NDIM + n, isbf);
    }
    *(bf16x8*)(W2S + (size_t)g*8) = v;
}

union U8 { bf16x8 v; unsigned u[4]; };

// relu(ha_bf16 + hb_f32) -> bf16 round-half-up, pair-packed
__device__ __forceinline__ bf16x8 mk_af(bf16x8 ha, const float* hb) {
    U8 r;
#pragma unroll
    for (int j = 0; j < 4; ++j) {
        float x0 = fmaxf((float)ha[2*j]   + hb[2*j],   0.f);
        float x1 = fmaxf((float)ha[2*j+1] + hb[2*j+1], 0.f);
        unsigned u0 = __float_as_uint(x0) + 0x8000u;
        unsigned u1 = __float_as_uint(x1) + 0x8000u;
        r.u[j] = (u0 >> 16) | (u1 & 0xFFFF0000u);
    }
    return r.v;
}

#define MFMA(a, b, c) __builtin_amdgcn_mfma_f32_16x16x32_bf16((a), (b), (c), 0, 0, 0)

// ---------------- main: fused pair MLP, 512 thr, tile m128(8i x 16j) x n512 ----------------
// 8 waves = 2 m-waves (m64) x 4 n-waves (n128); B double-buffered in LDS.
__global__ __launch_bounds__(512, 2) void pair_kernel(
        const ushort_t* __restrict__ HA, const ushort_t* __restrict__ HB,
        const ushort_t* __restrict__ W2S,
        const void* __restrict__ b2, const void* __restrict__ W3, const void* __restrict__ b3,
        const int* __restrict__ flag, void* __restrict__ out) {

    const int blkEnd[10] = {325,650,900,1150,1400,1725,2050,2297,2544,2791};
    const int aB[10]  = {0,0,0,0,200,200,200,550,400,400};
    const int bB[10]  = {200,0,400,550,400,200,0,0,200,0};
    const int NaT[10] = {200,200,200,200,200,200,200,150,150,150};
    const int NbT[10] = {200,200,150,150,150,200,200,200,200,200};
    const int jTl[10] = {13,13,10,10,10,13,13,13,13,13};
    const int oOf[10] = {0,80000,160000,220000,280000,340000,420000,500000,560000,620000};

    __shared__ ushort_t sB[2*16384];     // 65,536 B : B chunk ping-pong (32 KB each)
    __shared__ ushort_t sHA[8*1024];     // 16,384 B : 8 'a' rows, bf16
    __shared__ float    sHB[16*SBS];     // 65,792 B : 16 'b' rows, f32
    __shared__ float    lgt[4][128][2];  //  4,096 B

    int bid = blockIdx.x;
    int ty = 0;
    while (bid >= blkEnd[ty]) ty++;
    int lb = bid - (ty ? blkEnd[ty-1] : 0);
    int jT = jTl[ty];
    int it = lb / jT;
    int jt = lb - it*jT;
    int i0 = aB[ty] + it*8;    // 8 'a' rows per block
    int j0 = bB[ty] + jt*16;   // 16 'b' rows per block

    int tid  = threadIdx.x;
    int lane = tid & 63;
    int w    = tid >> 6;       // 0..7
    int wm   = w & 1;          // m-wave: i-rows wm*4 .. wm*4+3
    int wn   = w >> 1;         // n-wave: n128 quarter
    int l15  = lane & 15;
    int quad = lane >> 4;
    int isbf = *flag;

    // ---- stage sHA (bf16 copy, 8 rows) ----
#pragma unroll
    for (int ii = 0; ii < 2; ++ii) {
        int idx = tid + ii*512;            // 1024 frags of 8
        int r = idx >> 7, c = (idx & 127) << 3;
        *(bf16x8*)(sHA + r*1024 + c) = *(const bf16x8*)(HA + (i0 + r)*KDIM + c);
    }
    // ---- stage sHB (f32, 16 rows) — float4 writes, conflict-free ----
#pragma unroll
    for (int ii = 0; ii < 8; ++ii) {
        int idx = tid + ii*512;            // 4096 float4s
        int r = idx >> 8, c = (idx & 255) << 2;
        bf16x4 v = *(const bf16x4*)(HB + (j0 + r)*KDIM + c);
        float4 fv = { (float)v[0], (float)v[1], (float)v[2], (float)v[3] };
        *(float4*)(sHB + r*SBS + c) = fv;
    }
    // ---- stage B chunk 0 into buffer 0 ----
    {
        const uint4* g = (const uint4*)(W2S);
        uint4* d = (uint4*)sB;
#pragma unroll
        for (int ii = 0; ii < 4; ++ii) d[tid + ii*512] = g[tid + ii*512];
    }
    __syncthreads();

    floatx4 acc[4][8];
#pragma unroll
    for (int f = 0; f < 4; ++f)
#pragma unroll
        for (int nf = 0; nf < 8; ++nf) acc[f][nf] = (floatx4){0.f,0.f,0.f,0.f};

#pragma unroll 2
    for (int kc = 0; kc < 32; ++kc) {
        int nkc = (kc + 1) & 31;
        // prefetch next 32-KB B chunk (lands during this kc's compute)
        const uint4* g = (const uint4*)(W2S + nkc*16384);
        uint4 p0 = g[tid], p1 = g[tid + 512], p2 = g[tid + 1024], p3 = g[tid + 1536];

        // B fragments from LDS (frag-contiguous: base + lane*16B, conflict-free)
        const ushort_t* Bb = sB + (kc & 1)*16384 + (wn*8)*512 + lane*8;
        bf16x8 bfr[8];
#pragma unroll
        for (int nf = 0; nf < 8; ++nf) bfr[nf] = *(const bf16x8*)(Bb + nf*512);

        // A-gen: 4 i-rows, shared hb
        int ko = kc*32 + quad*8;
        const float* hbp = sHB + l15*SBS + ko;
        float hb[8];
        {
            float4 h0 = *(const float4*)(hbp);
            float4 h1 = *(const float4*)(hbp + 4);
            hb[0]=h0.x; hb[1]=h0.y; hb[2]=h0.z; hb[3]=h0.w;
            hb[4]=h1.x; hb[5]=h1.y; hb[6]=h1.z; hb[7]=h1.w;
        }
        bf16x8 af[4];
#pragma unroll
        for (int f = 0; f < 4; ++f) {
            bf16x8 hv = *(const bf16x8*)(sHA + (wm*4 + f)*1024 + ko);
            af[f] = mk_af(hv, hb);
        }
#pragma unroll
        for (int nf = 0; nf < 8; ++nf)
#pragma unroll
            for (int f = 0; f < 4; ++f)
                acc[f][nf] = MFMA(af[f], bfr[nf], acc[f][nf]);

        // commit prefetched chunk into the other buffer
        uint4* d = (uint4*)(sB + (nkc & 1)*16384);
        d[tid] = p0; d[tid + 512] = p1; d[tid + 1024] = p2; d[tid + 1536] = p3;
        __syncthreads();
    }

    // epilogue: h2 = relu(acc + b2); logits += h2 * W3; reduce over n
#pragma unroll
    for (int f = 0; f < 4; ++f) {
        float s0[4] = {0.f,0.f,0.f,0.f};
        float s1[4] = {0.f,0.f,0.f,0.f};
#pragma unroll
        for (int nf = 0; nf < 8; ++nf) {
            int n = wn*128 + nf*16 + l15;
            float b2v = ldin(b2, n, isbf);
            float wa  = ldin(W3, 2*n, isbf);
            float wb  = ldin(W3, 2*n+1, isbf);
            floatx4 c = acc[f][nf];
#pragma unroll
            for (int r = 0; r < 4; ++r) {
                float v = fmaxf(c[r] + b2v, 0.f);
                s0[r] += v * wa;
                s1[r] += v * wb;
            }
        }
#pragma unroll
        for (int off = 1; off < 16; off <<= 1) {
#pragma unroll
            for (int r = 0; r < 4; ++r) {
                s0[r] += __shfl_xor(s0[r], off, 64);
                s1[r] += __shfl_xor(s1[r], off, 64);
            }
        }
        if (l15 == 0) {
#pragma unroll
            for (int r = 0; r < 4; ++r) {
                int p = (wm*4 + f)*16 + quad*4 + r;   // i_local*16 + j_local
                lgt[wn][p][0] = s0[r];
                lgt[wn][p][1] = s1[r];
            }
        }
    }
    __syncthreads();

    if (tid < 128) {
        int p = tid;
        float l0 = lgt[0][p][0] + lgt[1][p][0] + lgt[2][p][0] + lgt[3][p][0] + ldin(b3, 0, isbf);
        float l1 = lgt[0][p][1] + lgt[1][p][1] + lgt[2][p][1] + lgt[3][p][1] + ldin(b3, 1, isbf);
        float mx = fmaxf(l0, l1);
        float e0 = __expf(l0 - mx), e1 = __expf(l1 - mx);
        float inv = 1.f / (e0 + e1);
        int pi = it*8 + (p >> 4), pj = jt*16 + (p & 15);
        if (pi < NaT[ty] && pj < NbT[ty]) {
            int o = oOf[ty] + (pi*NbT[ty] + pj)*2;
            if (isbf) {
                __hip_bfloat16* ob = (__hip_bfloat16*)out;
                ob[o]   = __float2bfloat16(e0 * inv);
                ob[o+1] = __float2bfloat16(e1 * inv);
            } else {
                float* of = (float*)out;
                of[o]   = e0 * inv;
                of[o+1] = e1 * inv;
            }
        }
    }
}

extern "C" void kernel_launch(void* const* d_in, const int* in_sizes, int n_in,
                              void* d_out, int out_size, void* d_ws, size_t ws_size,
                              hipStream_t stream) {
    const void* E    = d_in[1];
    const void* Went = d_in[3];
    const void* W1   = d_in[5];
    const void* b1   = d_in[6];
    const void* W2   = d_in[7];
    const void* b2   = d_in[8];
    const void* W3   = d_in[9];
    const void* b3   = d_in[10];

    char* ws = (char*)d_ws;
    __hip_bfloat16* HA   = (__hip_bfloat16*)(ws + WS_HA);
    __hip_bfloat16* HB   = (__hip_bfloat16*)(ws + WS_HB);
    __hip_bfloat16* W2S  = (__hip_bfloat16*)(ws + WS_W2S);
    float*          entf = (float*)(ws + WS_ENT);
    int*            flag = (int*)(ws + WS_FLAG);

    detect_kernel<<<dim3(1), dim3(64), 0, stream>>>((const ushort_t*)E, flag);
    ent_kernel<<<dim3(88), dim3(256), 0, stream>>>(E, Went, flag, entf, d_out);
    hab_kernel<<<dim3(89, 2), dim3(256), 0, stream>>>(entf, W1, b1, flag, HA, HB);
    prep_kernel<<<dim3(256), dim3(256), 0, stream>>>(W2, flag, W2S);
    pair_kernel<<<dim3(2791), dim3(512), 0, stream>>>((const ushort_t*)HA, (const ushort_t*)HB,
                                                      (const ushort_t*)W2S, b2, W3, b3, flag, d_out);
}